// Round 1
// baseline (461.798 us; speedup 1.0000x reference)
//
#include <hip/hip_runtime.h>

typedef __attribute__((ext_vector_type(4))) float f32x4;
typedef __attribute__((ext_vector_type(8))) short s16x8;
typedef __attribute__((ext_vector_type(8))) unsigned short u16x8;

#define AS1(p) ((const __attribute__((address_space(1))) void*)(p))
#define AS3(p) ((__attribute__((address_space(3))) void*)(p))

__device__ __forceinline__ unsigned short f2bf(float f) {
  unsigned u = __builtin_bit_cast(unsigned, f);
  u += 0x7fffu + ((u >> 16) & 1u);   // RNE; inputs are finite
  return (unsigned short)(u >> 16);
}
__device__ __forceinline__ float bf2f(unsigned short s) {
  unsigned u = ((unsigned)s) << 16;
  return __builtin_bit_cast(float, u);
}

// ---------------- fp32 -> bf16 cast (vectorized, grid-stride) ----------------
__global__ __launch_bounds__(256) void cast_bf16(const float* __restrict__ in,
                                                 unsigned short* __restrict__ out,
                                                 long n) {
  long i = ((long)blockIdx.x * 256 + threadIdx.x) * 4;
  long stride = (long)gridDim.x * 256 * 4;
  for (; i < n; i += stride) {
    float4 f = *(const float4*)(in + i);
    ushort4 o = { f2bf(f.x), f2bf(f.y), f2bf(f.z), f2bf(f.w) };
    *(ushort4*)(out + i) = o;
  }
}

// ---------------- hierarchical column cummax scan ----------------
// N_ROWS=8192, DIM=1024, CHUNK=64 rows, NCH=128 chunks
__global__ __launch_bounds__(256) void scan_chunkmax(const float* __restrict__ x,
                                                     float* __restrict__ partial) {
  int col = blockIdx.x * 256 + threadIdx.x;
  int chunk = blockIdx.y;
  const float* p = x + (long)chunk * 64 * 1024 + col;
  float m = -INFINITY;
#pragma unroll 4
  for (int i = 0; i < 64; i++) m = fmaxf(m, p[(long)i * 1024]);
  partial[chunk * 1024 + col] = m;
}

__global__ __launch_bounds__(256) void scan_chunkscan(const float* __restrict__ partial,
                                                      float* __restrict__ prefix,
                                                      float* __restrict__ suffix) {
  int col = blockIdx.x * 256 + threadIdx.x;
  float run = -INFINITY;
  for (int c = 0; c < 128; c++) {
    prefix[c * 1024 + col] = run;
    run = fmaxf(run, partial[c * 1024 + col]);
  }
  run = -INFINITY;
  for (int c = 127; c >= 0; c--) {
    suffix[c * 1024 + col] = run;
    run = fmaxf(run, partial[c * 1024 + col]);
  }
}

// Emits h_in bf16 [8192, 3072]: [:,0:1024]=x, [:,1024:2048]=before, [:,2048:3072]=after
__global__ __launch_bounds__(256) void scan_emit(const float* __restrict__ x,
                                                 const float* __restrict__ prefix,
                                                 const float* __restrict__ suffix,
                                                 unsigned short* __restrict__ h_in) {
  int col = blockIdx.x * 256 + threadIdx.x;
  int chunk = blockIdx.y;
  long r0 = (long)chunk * 64;
  float run = prefix[chunk * 1024 + col];
  for (int i = 0; i < 64; i++) {
    long row = r0 + i;
    float v = x[row * 1024 + col];
    unsigned short* hr = h_in + row * 3072;
    hr[col] = f2bf(v);
    hr[1024 + col] = f2bf(row == 0 ? 0.f : run);
    run = fmaxf(run, v);
  }
  float run2 = suffix[chunk * 1024 + col];
  for (int i = 63; i >= 0; i--) {
    long row = r0 + i;
    float v = x[row * 1024 + col];
    h_in[row * 3072 + 2048 + col] = f2bf(row == 8191 ? 0.f : run2);
    run2 = fmaxf(run2, v);
  }
}

// ---------------- m97-structure bf16 GEMM: C = A @ B^T ----------------
// A [M,K] bf16 row-major, B [N,K] bf16 row-major (i.e. B^T input).
// 128x128 tile, BK=32, 4 waves, 4x4 frags of 16x16x32 MFMA, global_load_lds w=16.
// EPI==1: Cb[row*N+col] = bf16(relu(acc + bias[col]))
// EPI==2: Cf[row*N+col] = (acc + bias[col]) * gamma[col] + resid[row*N+col]
template <int EPI>
__global__ __launch_bounds__(256) void gemm_bt(const unsigned short* __restrict__ A,
                                               const unsigned short* __restrict__ B,
                                               unsigned short* __restrict__ Cb,
                                               float* __restrict__ Cf,
                                               const float* __restrict__ bias,
                                               const float* __restrict__ gamma,
                                               const float* __restrict__ resid,
                                               int M, int N, int K) {
  constexpr int BM = 128, BN = 128, BK = 32;
  __shared__ unsigned short As[BM * BK];  // 8 KB, row-major [128][32]
  __shared__ unsigned short Bs[BN * BK];  // 8 KB
  const int tid = threadIdx.x;
  const int lane = tid & 63;
  const int wave = tid >> 6;
  const int wr = wave >> 1, wc = wave & 1;  // 2x2 waves, each 64x64 out
  const long brow = (long)blockIdx.y * BM;
  const long bcol = (long)blockIdx.x * BN;

  // staging: thread tid loads 16B to LDS byte tid*16 (+4096 for second half)
  // global row = (tid>>2) [+64], col elems = (tid&3)*8
  const unsigned short* Ag = A + (brow + (tid >> 2)) * (long)K + (tid & 3) * 8;
  const unsigned short* Bg = B + (bcol + (tid >> 2)) * (long)K + (tid & 3) * 8;
  const long rstep = (long)64 * K;

  f32x4 acc[4][4];
#pragma unroll
  for (int m = 0; m < 4; m++)
#pragma unroll
    for (int n = 0; n < 4; n++) acc[m][n] = (f32x4)0.f;

  const int fr = lane & 15, fk = lane >> 4;
  // s16x8 view: index = row*4 + kblock
  const s16x8* Af = ((const s16x8*)As) + (wr * 64 + fr) * 4 + fk;
  const s16x8* Bf = ((const s16x8*)Bs) + (wc * 64 + fr) * 4 + fk;

  for (int k0 = 0; k0 < K; k0 += BK) {
    __syncthreads();
    __builtin_amdgcn_global_load_lds(AS1(Ag + k0), AS3((char*)As + tid * 16), 16, 0, 0);
    __builtin_amdgcn_global_load_lds(AS1(Ag + k0 + rstep), AS3((char*)As + 4096 + tid * 16), 16, 0, 0);
    __builtin_amdgcn_global_load_lds(AS1(Bg + k0), AS3((char*)Bs + tid * 16), 16, 0, 0);
    __builtin_amdgcn_global_load_lds(AS1(Bg + k0 + rstep), AS3((char*)Bs + 4096 + tid * 16), 16, 0, 0);
    __syncthreads();
    s16x8 af[4], bg[4];
#pragma unroll
    for (int m = 0; m < 4; m++) af[m] = Af[m * 64];
#pragma unroll
    for (int n = 0; n < 4; n++) bg[n] = Bf[n * 64];
#pragma unroll
    for (int m = 0; m < 4; m++)
#pragma unroll
      for (int n = 0; n < 4; n++)
        acc[m][n] = __builtin_amdgcn_mfma_f32_16x16x32_bf16(af[m], bg[n], acc[m][n], 0, 0, 0);
  }

  // C/D layout: col = lane&15, row = (lane>>4)*4 + reg  [m89/m91 verified]
  const long orow = brow + wr * 64 + fk * 4;
  const long ocol = bcol + wc * 64 + fr;
#pragma unroll
  for (int m = 0; m < 4; m++) {
#pragma unroll
    for (int n = 0; n < 4; n++) {
      const long col = ocol + n * 16;
      const float bi = bias[col];
#pragma unroll
      for (int r = 0; r < 4; r++) {
        const long row = orow + m * 16 + r;
        float v = acc[m][n][r] + bi;
        if constexpr (EPI == 1) {
          v = v > 0.f ? v : 0.f;
          Cb[row * N + col] = f2bf(v);
        } else {
          Cf[row * N + col] = v * gamma[col] + resid[row * N + col];
        }
      }
    }
  }
}

// ---------------- in-place LayerNorm over D=4096, one block per row ----------------
__global__ __launch_bounds__(256) void ln_inplace(unsigned short* __restrict__ h,
                                                  const float* __restrict__ w,
                                                  const float* __restrict__ b) {
  unsigned short* hp = h + (long)blockIdx.x * 4096;
  const int tid = threadIdx.x;
  u16x8 a0 = ((const u16x8*)hp)[tid * 2];
  u16x8 a1 = ((const u16x8*)hp)[tid * 2 + 1];
  float v[16];
#pragma unroll
  for (int j = 0; j < 8; j++) { v[j] = bf2f(a0[j]); v[8 + j] = bf2f(a1[j]); }
  float s = 0.f, q = 0.f;
#pragma unroll
  for (int j = 0; j < 16; j++) { s += v[j]; q += v[j] * v[j]; }
#pragma unroll
  for (int off = 32; off; off >>= 1) {
    s += __shfl_xor(s, off, 64);
    q += __shfl_xor(q, off, 64);
  }
  __shared__ float ss[4], sq[4];
  const int wv = tid >> 6;
  if ((tid & 63) == 0) { ss[wv] = s; sq[wv] = q; }
  __syncthreads();
  s = ss[0] + ss[1] + ss[2] + ss[3];
  q = sq[0] + sq[1] + sq[2] + sq[3];
  const float mu = s * (1.f / 4096.f);
  const float var = q * (1.f / 4096.f) - mu * mu;
  const float rs = rsqrtf(var + 1e-6f);
  u16x8 o0, o1;
#pragma unroll
  for (int j = 0; j < 8; j++) {
    int c0 = tid * 16 + j, c1 = c0 + 8;
    o0[j] = f2bf((v[j] - mu) * rs * w[c0] + b[c0]);
    o1[j] = f2bf((v[8 + j] - mu) * rs * w[c1] + b[c1]);
  }
  ((u16x8*)hp)[tid * 2] = o0;
  ((u16x8*)hp)[tid * 2 + 1] = o1;
}

extern "C" void kernel_launch(void* const* d_in, const int* in_sizes, int n_in,
                              void* d_out, int out_size, void* d_ws, size_t ws_size,
                              hipStream_t stream) {
  const float* x     = (const float*)d_in[0];  // [8192,1024]
  const float* W1    = (const float*)d_in[1];  // [4096,3072]
  const float* b1    = (const float*)d_in[2];  // [4096]
  const float* ln_w  = (const float*)d_in[3];  // [4096]
  const float* ln_b  = (const float*)d_in[4];  // [4096]
  const float* W2    = (const float*)d_in[5];  // [1024,4096]
  const float* b2    = (const float*)d_in[6];  // [1024]
  const float* gamma = (const float*)d_in[7];  // [1024]
  float* out = (float*)d_out;

  const int Nr = 8192, DIM = 1024, DFF = 4096, K1 = 3072;

  // workspace layout (ushort elements unless noted)
  unsigned short* W1b  = (unsigned short*)d_ws;        // 12582912
  unsigned short* W2b  = W1b + (long)DFF * K1;          // 4194304
  unsigned short* h_in = W2b + (long)DIM * DFF;         // 25165824
  unsigned short* h_act = h_in + (long)Nr * K1;         // 33554432
  float* partial = (float*)(h_act + (long)Nr * DFF);    // 128*1024
  float* prefix  = partial + 128 * 1024;
  float* suffix  = prefix + 128 * 1024;

  // 1. weight casts
  cast_bf16<<<2048, 256, 0, stream>>>(W1, W1b, (long)DFF * K1);
  cast_bf16<<<1024, 256, 0, stream>>>(W2, W2b, (long)DIM * DFF);

  // 2. column cummax scan -> h_in (x | before | after) bf16
  scan_chunkmax<<<dim3(4, 128), 256, 0, stream>>>(x, partial);
  scan_chunkscan<<<4, 256, 0, stream>>>(partial, prefix, suffix);
  scan_emit<<<dim3(4, 128), 256, 0, stream>>>(x, prefix, suffix, h_in);

  // 3. h_act = relu(h_in @ W1^T + b1)   [8192,4096] bf16
  gemm_bt<1><<<dim3(DFF / 128, Nr / 128), 256, 0, stream>>>(
      h_in, W1b, h_act, nullptr, b1, nullptr, nullptr, Nr, DFF, K1);

  // 4. LayerNorm in place
  ln_inplace<<<Nr, 256, 0, stream>>>(h_act, ln_w, ln_b);

  // 5. out = (h_act @ W2^T + b2) * gamma + x
  gemm_bt<2><<<dim3(DIM / 128, Nr / 128), 256, 0, stream>>>(
      h_act, W2b, nullptr, out, b2, gamma, x, Nr, DIM, DFF);
}

// Round 2
// 395.830 us; speedup vs baseline: 1.1667x; 1.1667x over previous
//
#include <hip/hip_runtime.h>

typedef __attribute__((ext_vector_type(4))) float f32x4;
typedef __attribute__((ext_vector_type(8))) short s16x8;
typedef __attribute__((ext_vector_type(8))) unsigned short u16x8;

#define AS1(p) ((const __attribute__((address_space(1))) void*)(p))
#define AS3(p) ((__attribute__((address_space(3))) void*)(p))

__device__ __forceinline__ unsigned short f2bf(float f) {
  unsigned u = __builtin_bit_cast(unsigned, f);
  u += 0x7fffu + ((u >> 16) & 1u);   // RNE; inputs are finite
  return (unsigned short)(u >> 16);
}
__device__ __forceinline__ float bf2f(unsigned short s) {
  unsigned u = ((unsigned)s) << 16;
  return __builtin_bit_cast(float, u);
}

// ---------------- fp32 -> bf16 cast (vectorized, grid-stride) ----------------
__global__ __launch_bounds__(256) void cast_bf16(const float* __restrict__ in,
                                                 unsigned short* __restrict__ out,
                                                 long n) {
  long i = ((long)blockIdx.x * 256 + threadIdx.x) * 4;
  long stride = (long)gridDim.x * 256 * 4;
  for (; i < n; i += stride) {
    float4 f = *(const float4*)(in + i);
    ushort4 o = { f2bf(f.x), f2bf(f.y), f2bf(f.z), f2bf(f.w) };
    *(ushort4*)(out + i) = o;
  }
}

// ---------------- hierarchical column cummax scan ----------------
__global__ __launch_bounds__(256) void scan_chunkmax(const float* __restrict__ x,
                                                     float* __restrict__ partial) {
  int col = blockIdx.x * 256 + threadIdx.x;
  int chunk = blockIdx.y;
  const float* p = x + (long)chunk * 64 * 1024 + col;
  float m = -INFINITY;
#pragma unroll 4
  for (int i = 0; i < 64; i++) m = fmaxf(m, p[(long)i * 1024]);
  partial[chunk * 1024 + col] = m;
}

__global__ __launch_bounds__(256) void scan_chunkscan(const float* __restrict__ partial,
                                                      float* __restrict__ prefix,
                                                      float* __restrict__ suffix) {
  int col = blockIdx.x * 256 + threadIdx.x;
  float run = -INFINITY;
  for (int c = 0; c < 128; c++) {
    prefix[c * 1024 + col] = run;
    run = fmaxf(run, partial[c * 1024 + col]);
  }
  run = -INFINITY;
  for (int c = 127; c >= 0; c--) {
    suffix[c * 1024 + col] = run;
    run = fmaxf(run, partial[c * 1024 + col]);
  }
}

__global__ __launch_bounds__(256) void scan_emit(const float* __restrict__ x,
                                                 const float* __restrict__ prefix,
                                                 const float* __restrict__ suffix,
                                                 unsigned short* __restrict__ h_in) {
  int col = blockIdx.x * 256 + threadIdx.x;
  int chunk = blockIdx.y;
  long r0 = (long)chunk * 64;
  float run = prefix[chunk * 1024 + col];
  for (int i = 0; i < 64; i++) {
    long row = r0 + i;
    float v = x[row * 1024 + col];
    unsigned short* hr = h_in + row * 3072;
    hr[col] = f2bf(v);
    hr[1024 + col] = f2bf(row == 0 ? 0.f : run);
    run = fmaxf(run, v);
  }
  float run2 = suffix[chunk * 1024 + col];
  for (int i = 63; i >= 0; i--) {
    long row = r0 + i;
    float v = x[row * 1024 + col];
    h_in[row * 3072 + 2048 + col] = f2bf(row == 8191 ? 0.f : run2);
    run2 = fmaxf(run2, v);
  }
}

// ============ 256x256 8-phase bf16 GEMM (T1+T2+T3+T4+T5): C = relu(A@B^T + bias) ============
// A [M,K], B [N,K] bf16 row-major. 512 thr = 8 waves (2M x 4N), per-wave out 128x64.
// BK=64, dbuf LDS 128 KiB, st_16x32 swizzle, counted vmcnt, setprio MFMA clusters.
// Schedule (group g computes K-tile g from buf b=g&1; 4 phases/group):
//   group start: vmcnt(4) [last group: 0] + barrier  -> tile g fully landed
//   ph0: ds-read all 8 B-frags + A-frags m{0,1}; stage A(g+1) -> buf b^1 (4 loads)
//   ph1: ds-read A-frags m{2,3}; stage B(g+2) half0 -> buf b (read-done in ph0)
//   ph2: ds-read A-frags m{4,5}; stage B(g+2) half1 -> buf b
//   ph3: ds-read A-frags m{6,7}
//   each phase: barrier; lgkmcnt(0); setprio(1); 16 MFMA; setprio(0); barrier
__global__ __launch_bounds__(512, 2) void gemm256_relu(
    const unsigned short* __restrict__ A, const unsigned short* __restrict__ B,
    unsigned short* __restrict__ C, const float* __restrict__ bias,
    int M, int N, int K) {
  extern __shared__ char smem[];  // [buf][A 32K | B 32K] = 131072 B
  const int NT = K >> 6;          // K-tiles of 64

  // XCD-chunked swizzle (grid %8 == 0): each XCD gets contiguous swz range
  const int nwg = gridDim.x;
  const int cpx = nwg >> 3;
  const int bid = blockIdx.x;
  const int swz = (bid & 7) * cpx + (bid >> 3);
  const int tiles_m = M >> 8;
  const int tm = swz % tiles_m;
  const int tn = swz / tiles_m;
  const long brow = (long)tm * 256;
  const long bcol = (long)tn * 256;

  const int t = threadIdx.x;
  const int lane = t & 63, wv = t >> 6;
  const int wr = wv >> 2, wc = wv & 3;
  const int fr = lane & 15, fk = lane >> 4;

  // staging: thread t stages 16B; linear LDS dest (base + lane*16), inverse-
  // swizzled global source (rule #21). e=t*16 -> bit9=bit5(t), bit5=bit1(t).
  const int srow = t >> 3;
  const int scol = ((t & 7) * 8) ^ (((t >> 5) & 1) << 4);
  const unsigned short* Asrc = A + (brow + srow) * (long)K + scol;
  const unsigned short* Bsrc = B + (bcol + srow) * (long)K + scol;
  char* Adst = smem + t * 16;
  char* Bdst = smem + 32768 + t * 16;
  const long hstep = (long)128 * K, lstep = (long)64 * K;

#define STAGE_A(j, h, L)                                                      \
  __builtin_amdgcn_global_load_lds(AS1(Asrc + (h)*hstep + (L)*lstep + (j)*64),\
      AS3(Adst + ((j)&1) * 65536 + (h)*16384 + (L)*8192), 16, 0, 0)
#define STAGE_B(j, h, L)                                                      \
  __builtin_amdgcn_global_load_lds(AS1(Bsrc + (h)*hstep + (L)*lstep + (j)*64),\
      AS3(Bdst + ((j)&1) * 65536 + (h)*16384 + (L)*8192), 16, 0, 0)

  // ds_read: logical byte d = row*128 + kk*64 + fk*16; addr = d ^ ((bit9(d))<<5);
  // bit9(d) = bit2(row) = bit2(fr) for all frags here.
  const int xr5 = ((fr >> 2) & 1) << 5;
  const char* Ard = smem + (wr * 128 + fr) * 128;
  const char* Brd = smem + 32768 + (wc * 64 + fr) * 128;
#define RD_A(buf, m, kk) \
  (*(const s16x8*)(Ard + (buf)*65536 + (m)*2048 + (((kk)*64 + fk * 16) ^ xr5)))
#define RD_B(buf, n, kk) \
  (*(const s16x8*)(Brd + (buf)*65536 + (n)*2048 + (((kk)*64 + fk * 16) ^ xr5)))

  f32x4 acc[8][4];
#pragma unroll
  for (int m = 0; m < 8; m++)
#pragma unroll
    for (int n = 0; n < 4; n++) acc[m][n] = (f32x4)0.f;

  // prologue: tile0 A+B, tile1 B (12 loads; vmcnt(4) at group-0 start lands tile0)
  STAGE_A(0, 0, 0); STAGE_A(0, 0, 1); STAGE_A(0, 1, 0); STAGE_A(0, 1, 1);
  STAGE_B(0, 0, 0); STAGE_B(0, 0, 1); STAGE_B(0, 1, 0); STAGE_B(0, 1, 1);
  STAGE_B(1, 0, 0); STAGE_B(1, 0, 1); STAGE_B(1, 1, 0); STAGE_B(1, 1, 1);

  for (int g = 0; g < NT; ++g) {
    const int buf = g & 1;
    if (g + 1 < NT) asm volatile("s_waitcnt vmcnt(4)" ::: "memory");
    else            asm volatile("s_waitcnt vmcnt(0)" ::: "memory");
    __builtin_amdgcn_s_barrier();
    s16x8 bfr[4][2];
#pragma unroll
    for (int q = 0; q < 4; ++q) {
      if (q == 0) {
#pragma unroll
        for (int n = 0; n < 4; ++n) {
          bfr[n][0] = RD_B(buf, n, 0);
          bfr[n][1] = RD_B(buf, n, 1);
        }
      }
      s16x8 afr[2][2];
#pragma unroll
      for (int i = 0; i < 2; ++i) {
        afr[i][0] = RD_A(buf, 2 * q + i, 0);
        afr[i][1] = RD_A(buf, 2 * q + i, 1);
      }
      if (q == 0 && g + 1 < NT) {
        STAGE_A(g + 1, 0, 0); STAGE_A(g + 1, 0, 1);
        STAGE_A(g + 1, 1, 0); STAGE_A(g + 1, 1, 1);
      }
      if (q == 1 && g + 2 < NT) { STAGE_B(g + 2, 0, 0); STAGE_B(g + 2, 0, 1); }
      if (q == 2 && g + 2 < NT) { STAGE_B(g + 2, 1, 0); STAGE_B(g + 2, 1, 1); }
      __builtin_amdgcn_s_barrier();
      asm volatile("s_waitcnt lgkmcnt(0)" ::: "memory");
      __builtin_amdgcn_s_setprio(1);
#pragma unroll
      for (int i = 0; i < 2; ++i)
#pragma unroll
        for (int n = 0; n < 4; ++n) {
          acc[2 * q + i][n] = __builtin_amdgcn_mfma_f32_16x16x32_bf16(
              afr[i][0], bfr[n][0], acc[2 * q + i][n], 0, 0, 0);
          acc[2 * q + i][n] = __builtin_amdgcn_mfma_f32_16x16x32_bf16(
              afr[i][1], bfr[n][1], acc[2 * q + i][n], 0, 0, 0);
        }
      __builtin_amdgcn_s_setprio(0);
      __builtin_amdgcn_s_barrier();
    }
  }

  // epilogue: C/D layout col=lane&15, row=(lane>>4)*4+reg
  float bi[4];
#pragma unroll
  for (int n = 0; n < 4; ++n) bi[n] = bias[bcol + wc * 64 + n * 16 + fr];
  const long orow = brow + wr * 128 + fk * 4;
  const long ocol = bcol + wc * 64 + fr;
#pragma unroll
  for (int m = 0; m < 8; ++m)
#pragma unroll
    for (int n = 0; n < 4; ++n)
#pragma unroll
      for (int r = 0; r < 4; ++r) {
        float v = acc[m][n][r] + bi[n];
        v = v > 0.f ? v : 0.f;
        C[(orow + m * 16 + r) * (long)N + ocol + n * 16] = f2bf(v);
      }
#undef STAGE_A
#undef STAGE_B
#undef RD_A
#undef RD_B
}

// ---------------- m97-structure 128^2 bf16 GEMM (kept for N=1024 GEMM2) ----------------
// Cf[row*N+col] = (acc + bias[col]) * gamma[col] + resid[row*N+col]
__global__ __launch_bounds__(256) void gemm_bt2(const unsigned short* __restrict__ A,
                                                const unsigned short* __restrict__ B,
                                                float* __restrict__ Cf,
                                                const float* __restrict__ bias,
                                                const float* __restrict__ gamma,
                                                const float* __restrict__ resid,
                                                int M, int N, int K) {
  constexpr int BK = 32;
  __shared__ unsigned short As[128 * BK];
  __shared__ unsigned short Bs[128 * BK];
  const int tid = threadIdx.x;
  const int lane = tid & 63;
  const int wave = tid >> 6;
  const int wr = wave >> 1, wc = wave & 1;
  const long brow = (long)blockIdx.y * 128;
  const long bcol = (long)blockIdx.x * 128;

  const unsigned short* Ag = A + (brow + (tid >> 2)) * (long)K + (tid & 3) * 8;
  const unsigned short* Bg = B + (bcol + (tid >> 2)) * (long)K + (tid & 3) * 8;
  const long rstep = (long)64 * K;

  f32x4 acc[4][4];
#pragma unroll
  for (int m = 0; m < 4; m++)
#pragma unroll
    for (int n = 0; n < 4; n++) acc[m][n] = (f32x4)0.f;

  const int fr = lane & 15, fk = lane >> 4;
  const s16x8* Af = ((const s16x8*)As) + (wr * 64 + fr) * 4 + fk;
  const s16x8* Bf = ((const s16x8*)Bs) + (wc * 64 + fr) * 4 + fk;

  for (int k0 = 0; k0 < K; k0 += BK) {
    __syncthreads();
    __builtin_amdgcn_global_load_lds(AS1(Ag + k0), AS3((char*)As + tid * 16), 16, 0, 0);
    __builtin_amdgcn_global_load_lds(AS1(Ag + k0 + rstep), AS3((char*)As + 4096 + tid * 16), 16, 0, 0);
    __builtin_amdgcn_global_load_lds(AS1(Bg + k0), AS3((char*)Bs + tid * 16), 16, 0, 0);
    __builtin_amdgcn_global_load_lds(AS1(Bg + k0 + rstep), AS3((char*)Bs + 4096 + tid * 16), 16, 0, 0);
    __syncthreads();
    s16x8 af[4], bg[4];
#pragma unroll
    for (int m = 0; m < 4; m++) af[m] = Af[m * 64];
#pragma unroll
    for (int n = 0; n < 4; n++) bg[n] = Bf[n * 64];
#pragma unroll
    for (int m = 0; m < 4; m++)
#pragma unroll
      for (int n = 0; n < 4; n++)
        acc[m][n] = __builtin_amdgcn_mfma_f32_16x16x32_bf16(af[m], bg[n], acc[m][n], 0, 0, 0);
  }

  const long orow = brow + wr * 64 + fk * 4;
  const long ocol = bcol + wc * 64 + fr;
#pragma unroll
  for (int m = 0; m < 4; m++) {
#pragma unroll
    for (int n = 0; n < 4; n++) {
      const long col = ocol + n * 16;
      const float bi = bias[col];
      const float ga = gamma[col];
#pragma unroll
      for (int r = 0; r < 4; r++) {
        const long row = orow + m * 16 + r;
        Cf[row * N + col] = (acc[m][n][r] + bi) * ga + resid[row * N + col];
      }
    }
  }
}

// ---------------- in-place LayerNorm over D=4096, one block per row ----------------
__global__ __launch_bounds__(256) void ln_inplace(unsigned short* __restrict__ h,
                                                  const float* __restrict__ w,
                                                  const float* __restrict__ b) {
  unsigned short* hp = h + (long)blockIdx.x * 4096;
  const int tid = threadIdx.x;
  u16x8 a0 = ((const u16x8*)hp)[tid * 2];
  u16x8 a1 = ((const u16x8*)hp)[tid * 2 + 1];
  float v[16];
#pragma unroll
  for (int j = 0; j < 8; j++) { v[j] = bf2f(a0[j]); v[8 + j] = bf2f(a1[j]); }
  float s = 0.f, q = 0.f;
#pragma unroll
  for (int j = 0; j < 16; j++) { s += v[j]; q += v[j] * v[j]; }
#pragma unroll
  for (int off = 32; off; off >>= 1) {
    s += __shfl_xor(s, off, 64);
    q += __shfl_xor(q, off, 64);
  }
  __shared__ float ss[4], sq[4];
  const int wv = tid >> 6;
  if ((tid & 63) == 0) { ss[wv] = s; sq[wv] = q; }
  __syncthreads();
  s = ss[0] + ss[1] + ss[2] + ss[3];
  q = sq[0] + sq[1] + sq[2] + sq[3];
  const float mu = s * (1.f / 4096.f);
  const float var = q * (1.f / 4096.f) - mu * mu;
  const float rs = rsqrtf(var + 1e-6f);
  u16x8 o0, o1;
#pragma unroll
  for (int j = 0; j < 8; j++) {
    int c0 = tid * 16 + j, c1 = c0 + 8;
    o0[j] = f2bf((v[j] - mu) * rs * w[c0] + b[c0]);
    o1[j] = f2bf((v[8 + j] - mu) * rs * w[c1] + b[c1]);
  }
  ((u16x8*)hp)[tid * 2] = o0;
  ((u16x8*)hp)[tid * 2 + 1] = o1;
}

extern "C" void kernel_launch(void* const* d_in, const int* in_sizes, int n_in,
                              void* d_out, int out_size, void* d_ws, size_t ws_size,
                              hipStream_t stream) {
  const float* x     = (const float*)d_in[0];
  const float* W1    = (const float*)d_in[1];
  const float* b1    = (const float*)d_in[2];
  const float* ln_w  = (const float*)d_in[3];
  const float* ln_b  = (const float*)d_in[4];
  const float* W2    = (const float*)d_in[5];
  const float* b2    = (const float*)d_in[6];
  const float* gamma = (const float*)d_in[7];
  float* out = (float*)d_out;

  const int Nr = 8192, DIM = 1024, DFF = 4096, K1 = 3072;

  unsigned short* W1b  = (unsigned short*)d_ws;
  unsigned short* W2b  = W1b + (long)DFF * K1;
  unsigned short* h_in = W2b + (long)DIM * DFF;
  unsigned short* h_act = h_in + (long)Nr * K1;
  float* partial = (float*)(h_act + (long)Nr * DFF);
  float* prefix  = partial + 128 * 1024;
  float* suffix  = prefix + 128 * 1024;

  hipFuncSetAttribute((const void*)gemm256_relu,
                      hipFuncAttributeMaxDynamicSharedMemorySize, 131072);

  cast_bf16<<<2048, 256, 0, stream>>>(W1, W1b, (long)DFF * K1);
  cast_bf16<<<1024, 256, 0, stream>>>(W2, W2b, (long)DIM * DFF);

  scan_chunkmax<<<dim3(4, 128), 256, 0, stream>>>(x, partial);
  scan_chunkscan<<<4, 256, 0, stream>>>(partial, prefix, suffix);
  scan_emit<<<dim3(4, 128), 256, 0, stream>>>(x, prefix, suffix, h_in);

  // GEMM1: h_act = relu(h_in @ W1^T + b1)  — 256^2 8-phase, grid 32x16=512 (%8==0)
  gemm256_relu<<<512, 512, 131072, stream>>>(h_in, W1b, h_act, b1, Nr, DFF, K1);

  ln_inplace<<<Nr, 256, 0, stream>>>(h_act, ln_w, ln_b);

  // GEMM2: out = (h_act @ W2^T + b2) * gamma + x  — m97 128^2
  gemm_bt2<<<dim3(DIM / 128, Nr / 128), 256, 0, stream>>>(
      h_act, W2b, out, b2, gamma, x, Nr, DIM, DFF);
}

// Round 3
// 393.887 us; speedup vs baseline: 1.1724x; 1.0049x over previous
//
#include <hip/hip_runtime.h>

typedef __attribute__((ext_vector_type(4))) float f32x4;
typedef __attribute__((ext_vector_type(8))) short s16x8;
typedef __attribute__((ext_vector_type(8))) unsigned short u16x8;

#define AS1(p) ((const __attribute__((address_space(1))) void*)(p))
#define AS3(p) ((__attribute__((address_space(3))) void*)(p))

__device__ __forceinline__ unsigned short f2bf(float f) {
  unsigned u = __builtin_bit_cast(unsigned, f);
  u += 0x7fffu + ((u >> 16) & 1u);   // RNE; inputs are finite
  return (unsigned short)(u >> 16);
}
__device__ __forceinline__ float bf2f(unsigned short s) {
  unsigned u = ((unsigned)s) << 16;
  return __builtin_bit_cast(float, u);
}

// ---------------- fp32 -> bf16 cast (vectorized, grid-stride) ----------------
__global__ __launch_bounds__(256) void cast_bf16(const float* __restrict__ in,
                                                 unsigned short* __restrict__ out,
                                                 long n) {
  long i = ((long)blockIdx.x * 256 + threadIdx.x) * 4;
  long stride = (long)gridDim.x * 256 * 4;
  for (; i < n; i += stride) {
    float4 f = *(const float4*)(in + i);
    ushort4 o = { f2bf(f.x), f2bf(f.y), f2bf(f.z), f2bf(f.w) };
    *(ushort4*)(out + i) = o;
  }
}

// ---------------- hierarchical column cummax scan ----------------
__global__ __launch_bounds__(256) void scan_chunkmax(const float* __restrict__ x,
                                                     float* __restrict__ partial) {
  int col = blockIdx.x * 256 + threadIdx.x;
  int chunk = blockIdx.y;
  const float* p = x + (long)chunk * 64 * 1024 + col;
  float m = -INFINITY;
#pragma unroll 4
  for (int i = 0; i < 64; i++) m = fmaxf(m, p[(long)i * 1024]);
  partial[chunk * 1024 + col] = m;
}

__global__ __launch_bounds__(256) void scan_chunkscan(const float* __restrict__ partial,
                                                      float* __restrict__ prefix,
                                                      float* __restrict__ suffix) {
  int col = blockIdx.x * 256 + threadIdx.x;
  float run = -INFINITY;
  for (int c = 0; c < 128; c++) {
    prefix[c * 1024 + col] = run;
    run = fmaxf(run, partial[c * 1024 + col]);
  }
  run = -INFINITY;
  for (int c = 127; c >= 0; c--) {
    suffix[c * 1024 + col] = run;
    run = fmaxf(run, partial[c * 1024 + col]);
  }
}

__global__ __launch_bounds__(256) void scan_emit(const float* __restrict__ x,
                                                 const float* __restrict__ prefix,
                                                 const float* __restrict__ suffix,
                                                 unsigned short* __restrict__ h_in) {
  int col = blockIdx.x * 256 + threadIdx.x;
  int chunk = blockIdx.y;
  long r0 = (long)chunk * 64;
  float run = prefix[chunk * 1024 + col];
  for (int i = 0; i < 64; i++) {
    long row = r0 + i;
    float v = x[row * 1024 + col];
    unsigned short* hr = h_in + row * 3072;
    hr[col] = f2bf(v);
    hr[1024 + col] = f2bf(row == 0 ? 0.f : run);
    run = fmaxf(run, v);
  }
  float run2 = suffix[chunk * 1024 + col];
  for (int i = 63; i >= 0; i--) {
    long row = r0 + i;
    float v = x[row * 1024 + col];
    h_in[row * 3072 + 2048 + col] = f2bf(row == 8191 ? 0.f : run2);
    run2 = fmaxf(run2, v);
  }
}

// ============ 256x256 8-phase bf16 GEMM (T1+T2+T3+T4+T5): C = relu(A@B^T + bias) ============
// A [M,K], B [N,K] bf16 row-major. 512 thr = 8 waves (2M x 4N), per-wave out 128x64.
// BK=64, dbuf LDS 128 KiB, counted vmcnt, setprio MFMA clusters.
// LDS swizzle (fixed r3): swz(row) = bit2(row)<<5 | bit3(row)<<6 on the column byte.
//   Rationale: frag reads use 16-B slots {0,16,32,48}+kk*64 which is closed under
//   XOR-32 alone (r2's residual 2x conflict); adding bit3->bit6 spreads the 64
//   lanes over all 8 slots (8 lanes/slot = conflict-free floor).
// Applied as: linear LDS dest + inverse-swizzled GLOBAL source + swizzled ds_read
//   (both-sides rule; global_load_lds dest must stay linear).
__global__ __launch_bounds__(512, 2) void gemm256_relu(
    const unsigned short* __restrict__ A, const unsigned short* __restrict__ B,
    unsigned short* __restrict__ C, const float* __restrict__ bias,
    int M, int N, int K) {
  extern __shared__ char smem[];  // [buf][A 32K | B 32K] = 131072 B
  const int NT = K >> 6;          // K-tiles of 64

  // XCD-chunked swizzle (grid %8 == 0)
  const int nwg = gridDim.x;
  const int cpx = nwg >> 3;
  const int bid = blockIdx.x;
  const int swz = (bid & 7) * cpx + (bid >> 3);
  const int tiles_m = M >> 8;
  const int tm = swz % tiles_m;
  const int tn = swz / tiles_m;
  const long brow = (long)tm * 256;
  const long bcol = (long)tn * 256;

  const int t = threadIdx.x;
  const int lane = t & 63, wv = t >> 6;
  const int wr = wv >> 2, wc = wv & 3;
  const int fr = lane & 15, fk = lane >> 4;

  // staging: thread t stages 16B to linear LDS byte t*16 within the region.
  // row = t>>3, colbyte = (t&7)*16; source col pre-swizzled by swz(row):
  // bit2(row)=bit5(t)->col^16elem, bit3(row)=bit6(t)->col^32elem.
  const int srow = t >> 3;
  const int scol = ((t & 7) * 8) ^ (((t >> 5) & 1) << 4) ^ (((t >> 6) & 1) << 5);
  const unsigned short* Asrc = A + (brow + srow) * (long)K + scol;
  const unsigned short* Bsrc = B + (bcol + srow) * (long)K + scol;
  char* Adst = smem + t * 16;
  char* Bdst = smem + 32768 + t * 16;
  const long hstep = (long)128 * K, lstep = (long)64 * K;

#define STAGE_A(j, h, L)                                                      \
  __builtin_amdgcn_global_load_lds(AS1(Asrc + (h)*hstep + (L)*lstep + (j)*64),\
      AS3(Adst + ((j)&1) * 65536 + (h)*16384 + (L)*8192), 16, 0, 0)
#define STAGE_B(j, h, L)                                                      \
  __builtin_amdgcn_global_load_lds(AS1(Bsrc + (h)*hstep + (L)*lstep + (j)*64),\
      AS3(Bdst + ((j)&1) * 65536 + (h)*16384 + (L)*8192), 16, 0, 0)

  // ds_read: logical byte = row*128 + kk*64 + fk*16; addr ^= swz(row);
  // bit2(row)=bit2(fr), bit3(row)=bit3(fr) (m*16/n*16/wr*128/wc*64 are >=bit4).
  const int xr = (((fr >> 2) & 1) << 5) | (((fr >> 3) & 1) << 6);
  const char* Ard = smem + (wr * 128 + fr) * 128;
  const char* Brd = smem + 32768 + (wc * 64 + fr) * 128;
#define RD_A(buf, m, kk) \
  (*(const s16x8*)(Ard + (buf)*65536 + (m)*2048 + (((kk)*64 + fk * 16) ^ xr)))
#define RD_B(buf, n, kk) \
  (*(const s16x8*)(Brd + (buf)*65536 + (n)*2048 + (((kk)*64 + fk * 16) ^ xr)))

  f32x4 acc[8][4];
#pragma unroll
  for (int m = 0; m < 8; m++)
#pragma unroll
    for (int n = 0; n < 4; n++) acc[m][n] = (f32x4)0.f;

  // prologue: tile0 A+B, tile1 B
  STAGE_A(0, 0, 0); STAGE_A(0, 0, 1); STAGE_A(0, 1, 0); STAGE_A(0, 1, 1);
  STAGE_B(0, 0, 0); STAGE_B(0, 0, 1); STAGE_B(0, 1, 0); STAGE_B(0, 1, 1);
  STAGE_B(1, 0, 0); STAGE_B(1, 0, 1); STAGE_B(1, 1, 0); STAGE_B(1, 1, 1);

  for (int g = 0; g < NT; ++g) {
    const int buf = g & 1;
    if (g + 1 < NT) asm volatile("s_waitcnt vmcnt(4)" ::: "memory");
    else            asm volatile("s_waitcnt vmcnt(0)" ::: "memory");
    __builtin_amdgcn_s_barrier();
    s16x8 bfr[4][2];
#pragma unroll
    for (int q = 0; q < 4; ++q) {
      if (q == 0) {
#pragma unroll
        for (int n = 0; n < 4; ++n) {
          bfr[n][0] = RD_B(buf, n, 0);
          bfr[n][1] = RD_B(buf, n, 1);
        }
      }
      s16x8 afr[2][2];
#pragma unroll
      for (int i = 0; i < 2; ++i) {
        afr[i][0] = RD_A(buf, 2 * q + i, 0);
        afr[i][1] = RD_A(buf, 2 * q + i, 1);
      }
      if (q == 0 && g + 1 < NT) {
        STAGE_A(g + 1, 0, 0); STAGE_A(g + 1, 0, 1);
        STAGE_A(g + 1, 1, 0); STAGE_A(g + 1, 1, 1);
      }
      if (q == 1 && g + 2 < NT) { STAGE_B(g + 2, 0, 0); STAGE_B(g + 2, 0, 1); }
      if (q == 2 && g + 2 < NT) { STAGE_B(g + 2, 1, 0); STAGE_B(g + 2, 1, 1); }
      __builtin_amdgcn_s_barrier();
      asm volatile("s_waitcnt lgkmcnt(0)" ::: "memory");
      __builtin_amdgcn_s_setprio(1);
#pragma unroll
      for (int i = 0; i < 2; ++i)
#pragma unroll
        for (int n = 0; n < 4; ++n) {
          acc[2 * q + i][n] = __builtin_amdgcn_mfma_f32_16x16x32_bf16(
              afr[i][0], bfr[n][0], acc[2 * q + i][n], 0, 0, 0);
          acc[2 * q + i][n] = __builtin_amdgcn_mfma_f32_16x16x32_bf16(
              afr[i][1], bfr[n][1], acc[2 * q + i][n], 0, 0, 0);
        }
      __builtin_amdgcn_s_setprio(0);
      __builtin_amdgcn_s_barrier();
    }
  }

  // epilogue: C/D layout col=lane&15, row=(lane>>4)*4+reg
  float bi[4];
#pragma unroll
  for (int n = 0; n < 4; ++n) bi[n] = bias[bcol + wc * 64 + n * 16 + fr];
  const long orow = brow + wr * 128 + fk * 4;
  const long ocol = bcol + wc * 64 + fr;
#pragma unroll
  for (int m = 0; m < 8; ++m)
#pragma unroll
    for (int n = 0; n < 4; ++n)
#pragma unroll
      for (int r = 0; r < 4; ++r) {
        float v = acc[m][n][r] + bi[n];
        v = v > 0.f ? v : 0.f;
        C[(orow + m * 16 + r) * (long)N + ocol + n * 16] = f2bf(v);
      }
#undef STAGE_A
#undef STAGE_B
#undef RD_A
#undef RD_B
}

// ---------------- m97-structure 128^2 bf16 GEMM (N=1024 GEMM2) ----------------
__global__ __launch_bounds__(256) void gemm_bt2(const unsigned short* __restrict__ A,
                                                const unsigned short* __restrict__ B,
                                                float* __restrict__ Cf,
                                                const float* __restrict__ bias,
                                                const float* __restrict__ gamma,
                                                const float* __restrict__ resid,
                                                int M, int N, int K) {
  constexpr int BK = 32;
  __shared__ unsigned short As[128 * BK];
  __shared__ unsigned short Bs[128 * BK];
  const int tid = threadIdx.x;
  const int lane = tid & 63;
  const int wave = tid >> 6;
  const int wr = wave >> 1, wc = wave & 1;
  const long brow = (long)blockIdx.y * 128;
  const long bcol = (long)blockIdx.x * 128;

  const unsigned short* Ag = A + (brow + (tid >> 2)) * (long)K + (tid & 3) * 8;
  const unsigned short* Bg = B + (bcol + (tid >> 2)) * (long)K + (tid & 3) * 8;
  const long rstep = (long)64 * K;

  f32x4 acc[4][4];
#pragma unroll
  for (int m = 0; m < 4; m++)
#pragma unroll
    for (int n = 0; n < 4; n++) acc[m][n] = (f32x4)0.f;

  const int fr = lane & 15, fk = lane >> 4;
  const s16x8* Af = ((const s16x8*)As) + (wr * 64 + fr) * 4 + fk;
  const s16x8* Bf = ((const s16x8*)Bs) + (wc * 64 + fr) * 4 + fk;

  for (int k0 = 0; k0 < K; k0 += BK) {
    __syncthreads();
    __builtin_amdgcn_global_load_lds(AS1(Ag + k0), AS3((char*)As + tid * 16), 16, 0, 0);
    __builtin_amdgcn_global_load_lds(AS1(Ag + k0 + rstep), AS3((char*)As + 4096 + tid * 16), 16, 0, 0);
    __builtin_amdgcn_global_load_lds(AS1(Bg + k0), AS3((char*)Bs + tid * 16), 16, 0, 0);
    __builtin_amdgcn_global_load_lds(AS1(Bg + k0 + rstep), AS3((char*)Bs + 4096 + tid * 16), 16, 0, 0);
    __syncthreads();
    s16x8 af[4], bg[4];
#pragma unroll
    for (int m = 0; m < 4; m++) af[m] = Af[m * 64];
#pragma unroll
    for (int n = 0; n < 4; n++) bg[n] = Bf[n * 64];
#pragma unroll
    for (int m = 0; m < 4; m++)
#pragma unroll
      for (int n = 0; n < 4; n++)
        acc[m][n] = __builtin_amdgcn_mfma_f32_16x16x32_bf16(af[m], bg[n], acc[m][n], 0, 0, 0);
  }

  const long orow = brow + wr * 64 + fk * 4;
  const long ocol = bcol + wc * 64 + fr;
#pragma unroll
  for (int m = 0; m < 4; m++) {
#pragma unroll
    for (int n = 0; n < 4; n++) {
      const long col = ocol + n * 16;
      const float bi = bias[col];
      const float ga = gamma[col];
#pragma unroll
      for (int r = 0; r < 4; r++) {
        const long row = orow + m * 16 + r;
        Cf[row * N + col] = (acc[m][n][r] + bi) * ga + resid[row * N + col];
      }
    }
  }
}

// ---------------- in-place LayerNorm over D=4096, one block per row ----------------
__global__ __launch_bounds__(256) void ln_inplace(unsigned short* __restrict__ h,
                                                  const float* __restrict__ w,
                                                  const float* __restrict__ b) {
  unsigned short* hp = h + (long)blockIdx.x * 4096;
  const int tid = threadIdx.x;
  u16x8 a0 = ((const u16x8*)hp)[tid * 2];
  u16x8 a1 = ((const u16x8*)hp)[tid * 2 + 1];
  float v[16];
#pragma unroll
  for (int j = 0; j < 8; j++) { v[j] = bf2f(a0[j]); v[8 + j] = bf2f(a1[j]); }
  float s = 0.f, q = 0.f;
#pragma unroll
  for (int j = 0; j < 16; j++) { s += v[j]; q += v[j] * v[j]; }
#pragma unroll
  for (int off = 32; off; off >>= 1) {
    s += __shfl_xor(s, off, 64);
    q += __shfl_xor(q, off, 64);
  }
  __shared__ float ss[4], sq[4];
  const int wv = tid >> 6;
  if ((tid & 63) == 0) { ss[wv] = s; sq[wv] = q; }
  __syncthreads();
  s = ss[0] + ss[1] + ss[2] + ss[3];
  q = sq[0] + sq[1] + sq[2] + sq[3];
  const float mu = s * (1.f / 4096.f);
  const float var = q * (1.f / 4096.f) - mu * mu;
  const float rs = rsqrtf(var + 1e-6f);
  u16x8 o0, o1;
#pragma unroll
  for (int j = 0; j < 8; j++) {
    int c0 = tid * 16 + j, c1 = c0 + 8;
    o0[j] = f2bf((v[j] - mu) * rs * w[c0] + b[c0]);
    o1[j] = f2bf((v[8 + j] - mu) * rs * w[c1] + b[c1]);
  }
  ((u16x8*)hp)[tid * 2] = o0;
  ((u16x8*)hp)[tid * 2 + 1] = o1;
}

extern "C" void kernel_launch(void* const* d_in, const int* in_sizes, int n_in,
                              void* d_out, int out_size, void* d_ws, size_t ws_size,
                              hipStream_t stream) {
  const float* x     = (const float*)d_in[0];
  const float* W1    = (const float*)d_in[1];
  const float* b1    = (const float*)d_in[2];
  const float* ln_w  = (const float*)d_in[3];
  const float* ln_b  = (const float*)d_in[4];
  const float* W2    = (const float*)d_in[5];
  const float* b2    = (const float*)d_in[6];
  const float* gamma = (const float*)d_in[7];
  float* out = (float*)d_out;

  const int Nr = 8192, DIM = 1024, DFF = 4096, K1 = 3072;

  unsigned short* W1b  = (unsigned short*)d_ws;
  unsigned short* W2b  = W1b + (long)DFF * K1;
  unsigned short* h_in = W2b + (long)DIM * DFF;
  unsigned short* h_act = h_in + (long)Nr * K1;
  float* partial = (float*)(h_act + (long)Nr * DFF);
  float* prefix  = partial + 128 * 1024;
  float* suffix  = prefix + 128 * 1024;

  hipFuncSetAttribute((const void*)gemm256_relu,
                      hipFuncAttributeMaxDynamicSharedMemorySize, 131072);

  cast_bf16<<<2048, 256, 0, stream>>>(W1, W1b, (long)DFF * K1);
  cast_bf16<<<1024, 256, 0, stream>>>(W2, W2b, (long)DIM * DFF);

  scan_chunkmax<<<dim3(4, 128), 256, 0, stream>>>(x, partial);
  scan_chunkscan<<<4, 256, 0, stream>>>(partial, prefix, suffix);
  scan_emit<<<dim3(4, 128), 256, 0, stream>>>(x, prefix, suffix, h_in);

  // GEMM1: h_act = relu(h_in @ W1^T + b1)  — 256^2 8-phase, grid 32x16=512
  gemm256_relu<<<512, 512, 131072, stream>>>(h_in, W1b, h_act, b1, Nr, DFF, K1);

  ln_inplace<<<Nr, 256, 0, stream>>>(h_act, ln_w, ln_b);

  // GEMM2: out = (h_act @ W2^T + b2) * gamma + x  — m97 128^2
  gemm_bt2<<<dim3(DIM / 128, Nr / 128), 256, 0, stream>>>(
      h_act, W2b, out, b2, gamma, x, Nr, DIM, DFF);
}

// Round 4
// 387.220 us; speedup vs baseline: 1.1926x; 1.0172x over previous
//
#include <hip/hip_runtime.h>

typedef __attribute__((ext_vector_type(4))) float f32x4;
typedef __attribute__((ext_vector_type(8))) short s16x8;
typedef __attribute__((ext_vector_type(8))) unsigned short u16x8;

#define AS1(p) ((const __attribute__((address_space(1))) void*)(p))
#define AS3(p) ((__attribute__((address_space(3))) void*)(p))

__device__ __forceinline__ unsigned short f2bf(float f) {
  unsigned u = __builtin_bit_cast(unsigned, f);
  u += 0x7fffu + ((u >> 16) & 1u);   // RNE; inputs are finite
  return (unsigned short)(u >> 16);
}
__device__ __forceinline__ float bf2f(unsigned short s) {
  unsigned u = ((unsigned)s) << 16;
  return __builtin_bit_cast(float, u);
}

// ---------------- fp32 -> bf16 cast (vectorized, grid-stride) ----------------
__global__ __launch_bounds__(256) void cast_bf16(const float* __restrict__ in,
                                                 unsigned short* __restrict__ out,
                                                 long n) {
  long i = ((long)blockIdx.x * 256 + threadIdx.x) * 4;
  long stride = (long)gridDim.x * 256 * 4;
  for (; i < n; i += stride) {
    float4 f = *(const float4*)(in + i);
    ushort4 o = { f2bf(f.x), f2bf(f.y), f2bf(f.z), f2bf(f.w) };
    *(ushort4*)(out + i) = o;
  }
}

// ---------------- hierarchical column cummax scan ----------------
__global__ __launch_bounds__(256) void scan_chunkmax(const float* __restrict__ x,
                                                     float* __restrict__ partial) {
  int col = blockIdx.x * 256 + threadIdx.x;
  int chunk = blockIdx.y;
  const float* p = x + (long)chunk * 64 * 1024 + col;
  float m = -INFINITY;
#pragma unroll 4
  for (int i = 0; i < 64; i++) m = fmaxf(m, p[(long)i * 1024]);
  partial[chunk * 1024 + col] = m;
}

__global__ __launch_bounds__(256) void scan_chunkscan(const float* __restrict__ partial,
                                                      float* __restrict__ prefix,
                                                      float* __restrict__ suffix) {
  int col = blockIdx.x * 256 + threadIdx.x;
  float run = -INFINITY;
  for (int c = 0; c < 128; c++) {
    prefix[c * 1024 + col] = run;
    run = fmaxf(run, partial[c * 1024 + col]);
  }
  run = -INFINITY;
  for (int c = 127; c >= 0; c--) {
    suffix[c * 1024 + col] = run;
    run = fmaxf(run, partial[c * 1024 + col]);
  }
}

__global__ __launch_bounds__(256) void scan_emit(const float* __restrict__ x,
                                                 const float* __restrict__ prefix,
                                                 const float* __restrict__ suffix,
                                                 unsigned short* __restrict__ h_in) {
  int col = blockIdx.x * 256 + threadIdx.x;
  int chunk = blockIdx.y;
  long r0 = (long)chunk * 64;
  float run = prefix[chunk * 1024 + col];
  for (int i = 0; i < 64; i++) {
    long row = r0 + i;
    float v = x[row * 1024 + col];
    unsigned short* hr = h_in + row * 3072;
    hr[col] = f2bf(v);
    hr[1024 + col] = f2bf(row == 0 ? 0.f : run);
    run = fmaxf(run, v);
  }
  float run2 = suffix[chunk * 1024 + col];
  for (int i = 63; i >= 0; i--) {
    long row = r0 + i;
    float v = x[row * 1024 + col];
    h_in[row * 3072 + 2048 + col] = f2bf(row == 8191 ? 0.f : run2);
    run2 = fmaxf(run2, v);
  }
}

// ============ 256x256 8-phase bf16 GEMM: C = relu(A@B^T + bias) ============
// A [M,K], B [N,K] bf16 row-major. 512 thr = 8 waves (2M x 4N), per-wave out 128x64.
// BK=64, dbuf LDS 128 KiB, counted vmcnt, setprio MFMA clusters.
// LDS swizzle (r4): byte ^= (row&7)<<4 (all THREE low row bits into the 16B-slot
//   index). slot = (kk*4+fk) ^ (fr&7): uniform 8 lanes/slot full-wave AND 2
//   lanes/slot per fixed-fk quarter-wave — conflict-free at every granularity.
//   (r2/r3 2-bit variants left 4 extra cy/read: slots under-covered sub-wave.)
// Applied as: linear LDS dest + inverse-swizzled GLOBAL source + swizzled ds_read.
__global__ __launch_bounds__(512, 2) void gemm256_relu(
    const unsigned short* __restrict__ A, const unsigned short* __restrict__ B,
    unsigned short* __restrict__ C, const float* __restrict__ bias,
    int M, int N, int K) {
  extern __shared__ char smem[];  // [buf][A 32K | B 32K] = 131072 B
  const int NT = K >> 6;          // K-tiles of 64

  // XCD-chunked swizzle (grid %8 == 0)
  const int nwg = gridDim.x;
  const int cpx = nwg >> 3;
  const int bid = blockIdx.x;
  const int swz = (bid & 7) * cpx + (bid >> 3);
  const int tiles_m = M >> 8;
  const int tm = swz % tiles_m;
  const int tn = swz / tiles_m;
  const long brow = (long)tm * 256;
  const long bcol = (long)tn * 256;

  const int t = threadIdx.x;
  const int lane = t & 63, wv = t >> 6;
  const int wr = wv >> 2, wc = wv & 3;
  const int fr = lane & 15, fk = lane >> 4;

  // staging: thread t -> linear LDS byte t*16; row=t>>3, physical colbyte=(t&7)*16.
  // logical col = physical ^ ((row&7)<<4)  ->  scol elems = 8*((t&7) ^ ((t>>3)&7)).
  const int srow = t >> 3;
  const int scol = 8 * ((t & 7) ^ ((t >> 3) & 7));
  const unsigned short* Asrc = A + (brow + srow) * (long)K + scol;
  const unsigned short* Bsrc = B + (bcol + srow) * (long)K + scol;
  char* Adst = smem + t * 16;
  char* Bdst = smem + 32768 + t * 16;
  const long hstep = (long)128 * K, lstep = (long)64 * K;

#define STAGE_A(j, h, L)                                                      \
  __builtin_amdgcn_global_load_lds(AS1(Asrc + (h)*hstep + (L)*lstep + (j)*64),\
      AS3(Adst + ((j)&1) * 65536 + (h)*16384 + (L)*8192), 16, 0, 0)
#define STAGE_B(j, h, L)                                                      \
  __builtin_amdgcn_global_load_lds(AS1(Bsrc + (h)*hstep + (L)*lstep + (j)*64),\
      AS3(Bdst + ((j)&1) * 65536 + (h)*16384 + (L)*8192), 16, 0, 0)

  // ds_read: logical byte = row*128 + kk*64 + fk*16; physical ^= (row&7)<<4;
  // row&7 = fr&7 (m*16/n*16/wr*128/wc*64 all have zero low-3 row bits).
  const int xr = (fr & 7) << 4;
  const char* Ard = smem + (wr * 128 + fr) * 128;
  const char* Brd = smem + 32768 + (wc * 64 + fr) * 128;
#define RD_A(buf, m, kk) \
  (*(const s16x8*)(Ard + (buf)*65536 + (m)*2048 + (((kk)*64 + fk * 16) ^ xr)))
#define RD_B(buf, n, kk) \
  (*(const s16x8*)(Brd + (buf)*65536 + (n)*2048 + (((kk)*64 + fk * 16) ^ xr)))

  f32x4 acc[8][4];
#pragma unroll
  for (int m = 0; m < 8; m++)
#pragma unroll
    for (int n = 0; n < 4; n++) acc[m][n] = (f32x4)0.f;

  // prologue: tile0 A+B, tile1 B
  STAGE_A(0, 0, 0); STAGE_A(0, 0, 1); STAGE_A(0, 1, 0); STAGE_A(0, 1, 1);
  STAGE_B(0, 0, 0); STAGE_B(0, 0, 1); STAGE_B(0, 1, 0); STAGE_B(0, 1, 1);
  STAGE_B(1, 0, 0); STAGE_B(1, 0, 1); STAGE_B(1, 1, 0); STAGE_B(1, 1, 1);

  for (int g = 0; g < NT; ++g) {
    const int buf = g & 1;
    if (g + 1 < NT) asm volatile("s_waitcnt vmcnt(4)" ::: "memory");
    else            asm volatile("s_waitcnt vmcnt(0)" ::: "memory");
    __builtin_amdgcn_s_barrier();
    s16x8 bfr[4][2];
#pragma unroll
    for (int q = 0; q < 4; ++q) {
      if (q == 0) {
#pragma unroll
        for (int n = 0; n < 4; ++n) {
          bfr[n][0] = RD_B(buf, n, 0);
          bfr[n][1] = RD_B(buf, n, 1);
        }
      }
      s16x8 afr[2][2];
#pragma unroll
      for (int i = 0; i < 2; ++i) {
        afr[i][0] = RD_A(buf, 2 * q + i, 0);
        afr[i][1] = RD_A(buf, 2 * q + i, 1);
      }
      if (q == 0 && g + 1 < NT) {
        STAGE_A(g + 1, 0, 0); STAGE_A(g + 1, 0, 1);
        STAGE_A(g + 1, 1, 0); STAGE_A(g + 1, 1, 1);
      }
      if (q == 1 && g + 2 < NT) { STAGE_B(g + 2, 0, 0); STAGE_B(g + 2, 0, 1); }
      if (q == 2 && g + 2 < NT) { STAGE_B(g + 2, 1, 0); STAGE_B(g + 2, 1, 1); }
      __builtin_amdgcn_s_barrier();
      asm volatile("s_waitcnt lgkmcnt(0)" ::: "memory");
      __builtin_amdgcn_s_setprio(1);
#pragma unroll
      for (int i = 0; i < 2; ++i)
#pragma unroll
        for (int n = 0; n < 4; ++n) {
          acc[2 * q + i][n] = __builtin_amdgcn_mfma_f32_16x16x32_bf16(
              afr[i][0], bfr[n][0], acc[2 * q + i][n], 0, 0, 0);
          acc[2 * q + i][n] = __builtin_amdgcn_mfma_f32_16x16x32_bf16(
              afr[i][1], bfr[n][1], acc[2 * q + i][n], 0, 0, 0);
        }
      __builtin_amdgcn_s_setprio(0);
      __builtin_amdgcn_s_barrier();
    }
  }

  // epilogue: C/D layout col=lane&15, row=(lane>>4)*4+reg
  float bi[4];
#pragma unroll
  for (int n = 0; n < 4; ++n) bi[n] = bias[bcol + wc * 64 + n * 16 + fr];
  const long orow = brow + wr * 128 + fk * 4;
  const long ocol = bcol + wc * 64 + fr;
#pragma unroll
  for (int m = 0; m < 8; ++m)
#pragma unroll
    for (int n = 0; n < 4; ++n)
#pragma unroll
      for (int r = 0; r < 4; ++r) {
        float v = acc[m][n][r] + bi[n];
        v = v > 0.f ? v : 0.f;
        C[(orow + m * 16 + r) * (long)N + ocol + n * 16] = f2bf(v);
      }
#undef STAGE_A
#undef STAGE_B
#undef RD_A
#undef RD_B
}

// ---------------- m97-structure 128^2 bf16 GEMM (N=1024 GEMM2) ----------------
// LDS rows are 64 B here -> only byte bits 4-5 swizzlable: byte ^= ((row>>1)&3)<<4
// (slot period 128B spans 2 rows; row&1 already feeds slot bit 2). Uniform at
// full- and quarter-wave. Source pre-swizzled to match (both-sides rule).
__global__ __launch_bounds__(256) void gemm_bt2(const unsigned short* __restrict__ A,
                                                const unsigned short* __restrict__ B,
                                                float* __restrict__ Cf,
                                                const float* __restrict__ bias,
                                                const float* __restrict__ gamma,
                                                const float* __restrict__ resid,
                                                int M, int N, int K) {
  constexpr int BK = 32;
  __shared__ unsigned short As[128 * BK];
  __shared__ unsigned short Bs[128 * BK];
  const int tid = threadIdx.x;
  const int lane = tid & 63;
  const int wave = tid >> 6;
  const int wr = wave >> 1, wc = wave & 1;
  const long brow = (long)blockIdx.y * 128;
  const long bcol = (long)blockIdx.x * 128;

  // staging: dest byte tid*16, row=tid>>2, physical colbyte=(tid&3)*16;
  // logical col = physical ^ ((row>>1)&3)<<4 -> scol elems = (tid&3)*8 ^ ((tid>>3)&3)<<3
  const int scol = ((tid & 3) * 8) ^ ((((tid >> 3) & 3)) << 3);
  const unsigned short* Ag = A + (brow + (tid >> 2)) * (long)K + scol;
  const unsigned short* Bg = B + (bcol + (tid >> 2)) * (long)K + scol;
  const long rstep = (long)64 * K;

  f32x4 acc[4][4];
#pragma unroll
  for (int m = 0; m < 4; m++)
#pragma unroll
    for (int n = 0; n < 4; n++) acc[m][n] = (f32x4)0.f;

  const int fr = lane & 15, fk = lane >> 4;
  // read: row = (wr|wc)*64 + m*16 + fr (64B rows); byte-in-row = fk*16 ^ xr2
  const int xr2 = ((fr >> 1) & 3) << 4;
  const char* Ard = (const char*)As + (wr * 64 + fr) * 64;
  const char* Brd = (const char*)Bs + (wc * 64 + fr) * 64;
#define RD2_A(m) (*(const s16x8*)(Ard + (m)*1024 + (fk * 16 ^ xr2)))
#define RD2_B(n) (*(const s16x8*)(Brd + (n)*1024 + (fk * 16 ^ xr2)))

  for (int k0 = 0; k0 < K; k0 += BK) {
    __syncthreads();
    __builtin_amdgcn_global_load_lds(AS1(Ag + k0), AS3((char*)As + tid * 16), 16, 0, 0);
    __builtin_amdgcn_global_load_lds(AS1(Ag + k0 + rstep), AS3((char*)As + 4096 + tid * 16), 16, 0, 0);
    __builtin_amdgcn_global_load_lds(AS1(Bg + k0), AS3((char*)Bs + tid * 16), 16, 0, 0);
    __builtin_amdgcn_global_load_lds(AS1(Bg + k0 + rstep), AS3((char*)Bs + 4096 + tid * 16), 16, 0, 0);
    __syncthreads();
    s16x8 af[4], bg[4];
#pragma unroll
    for (int m = 0; m < 4; m++) af[m] = RD2_A(m);
#pragma unroll
    for (int n = 0; n < 4; n++) bg[n] = RD2_B(n);
#pragma unroll
    for (int m = 0; m < 4; m++)
#pragma unroll
      for (int n = 0; n < 4; n++)
        acc[m][n] = __builtin_amdgcn_mfma_f32_16x16x32_bf16(af[m], bg[n], acc[m][n], 0, 0, 0);
  }
#undef RD2_A
#undef RD2_B

  const long orow = brow + wr * 64 + fk * 4;
  const long ocol = bcol + wc * 64 + fr;
#pragma unroll
  for (int m = 0; m < 4; m++) {
#pragma unroll
    for (int n = 0; n < 4; n++) {
      const long col = ocol + n * 16;
      const float bi = bias[col];
      const float ga = gamma[col];
#pragma unroll
      for (int r = 0; r < 4; r++) {
        const long row = orow + m * 16 + r;
        Cf[row * N + col] = (acc[m][n][r] + bi) * ga + resid[row * N + col];
      }
    }
  }
}

// ---------------- in-place LayerNorm over D=4096, one block per row ----------------
__global__ __launch_bounds__(256) void ln_inplace(unsigned short* __restrict__ h,
                                                  const float* __restrict__ w,
                                                  const float* __restrict__ b) {
  unsigned short* hp = h + (long)blockIdx.x * 4096;
  const int tid = threadIdx.x;
  u16x8 a0 = ((const u16x8*)hp)[tid * 2];
  u16x8 a1 = ((const u16x8*)hp)[tid * 2 + 1];
  float v[16];
#pragma unroll
  for (int j = 0; j < 8; j++) { v[j] = bf2f(a0[j]); v[8 + j] = bf2f(a1[j]); }
  float s = 0.f, q = 0.f;
#pragma unroll
  for (int j = 0; j < 16; j++) { s += v[j]; q += v[j] * v[j]; }
#pragma unroll
  for (int off = 32; off; off >>= 1) {
    s += __shfl_xor(s, off, 64);
    q += __shfl_xor(q, off, 64);
  }
  __shared__ float ss[4], sq[4];
  const int wv = tid >> 6;
  if ((tid & 63) == 0) { ss[wv] = s; sq[wv] = q; }
  __syncthreads();
  s = ss[0] + ss[1] + ss[2] + ss[3];
  q = sq[0] + sq[1] + sq[2] + sq[3];
  const float mu = s * (1.f / 4096.f);
  const float var = q * (1.f / 4096.f) - mu * mu;
  const float rs = rsqrtf(var + 1e-6f);
  u16x8 o0, o1;
#pragma unroll
  for (int j = 0; j < 8; j++) {
    int c0 = tid * 16 + j, c1 = c0 + 8;
    o0[j] = f2bf((v[j] - mu) * rs * w[c0] + b[c0]);
    o1[j] = f2bf((v[8 + j] - mu) * rs * w[c1] + b[c1]);
  }
  ((u16x8*)hp)[tid * 2] = o0;
  ((u16x8*)hp)[tid * 2 + 1] = o1;
}

extern "C" void kernel_launch(void* const* d_in, const int* in_sizes, int n_in,
                              void* d_out, int out_size, void* d_ws, size_t ws_size,
                              hipStream_t stream) {
  const float* x     = (const float*)d_in[0];
  const float* W1    = (const float*)d_in[1];
  const float* b1    = (const float*)d_in[2];
  const float* ln_w  = (const float*)d_in[3];
  const float* ln_b  = (const float*)d_in[4];
  const float* W2    = (const float*)d_in[5];
  const float* b2    = (const float*)d_in[6];
  const float* gamma = (const float*)d_in[7];
  float* out = (float*)d_out;

  const int Nr = 8192, DIM = 1024, DFF = 4096, K1 = 3072;

  unsigned short* W1b  = (unsigned short*)d_ws;
  unsigned short* W2b  = W1b + (long)DFF * K1;
  unsigned short* h_in = W2b + (long)DIM * DFF;
  unsigned short* h_act = h_in + (long)Nr * K1;
  float* partial = (float*)(h_act + (long)Nr * DFF);
  float* prefix  = partial + 128 * 1024;
  float* suffix  = prefix + 128 * 1024;

  hipFuncSetAttribute((const void*)gemm256_relu,
                      hipFuncAttributeMaxDynamicSharedMemorySize, 131072);

  cast_bf16<<<2048, 256, 0, stream>>>(W1, W1b, (long)DFF * K1);
  cast_bf16<<<1024, 256, 0, stream>>>(W2, W2b, (long)DIM * DFF);

  scan_chunkmax<<<dim3(4, 128), 256, 0, stream>>>(x, partial);
  scan_chunkscan<<<4, 256, 0, stream>>>(partial, prefix, suffix);
  scan_emit<<<dim3(4, 128), 256, 0, stream>>>(x, prefix, suffix, h_in);

  // GEMM1: h_act = relu(h_in @ W1^T + b1)  — 256^2 8-phase, grid 32x16=512
  gemm256_relu<<<512, 512, 131072, stream>>>(h_in, W1b, h_act, b1, Nr, DFF, K1);

  ln_inplace<<<Nr, 256, 0, stream>>>(h_act, ln_w, ln_b);

  // GEMM2: out = (h_act @ W2^T + b2) * gamma + x  — m97 128^2
  gemm_bt2<<<dim3(DIM / 128, Nr / 128), 256, 0, stream>>>(
      h_act, W2b, out, b2, gamma, x, Nr, DIM, DFF);
}